// Round 14
// baseline (3951.884 us; speedup 1.0000x reference)
//
#include <hip/hip_runtime.h>
#include <math.h>

#define B_ROWS 32768
#define DIM    1024
#define PA 132
#define PB 68

// Numerics contract (verified r10-r13, absmax 0.0): BLIS sgemm, KC=512.
// Per C element: p1 = serial ascending FMA chain k=0..511, p2 = k=512..1023,
// C = fl(p1+p2). Chunks 0..15 -> acc1 (=p1), 16..31 -> acc2 (=p2).
//
// VGPR discipline (r12/r13 lessons): occupancy buckets at VGPR {64,128,256};
// dual accumulators (64 regs) + direct staging lands ~108 -> bucket 128 ->
// 4 waves/SIMD. Register prefetch (+24 regs) crossed into bucket 256 ->
// 2 waves/SIMD and LOST time. So: direct staging, no prefetch fragment,
// no min-occupancy launch_bounds.

__device__ __forceinline__ void computeT(const float (*As)[PA], const float (*Bs)[PB],
                                         int tx, int ty, float (&acc)[8][4]) {
#pragma unroll
    for (int kk = 0; kk < 32; ++kk) {
        const int h = (kk >> 2) & 3;
        const float4 a0 = *(const float4*)&As[kk][((ty + h) & 15) * 8];
        const float4 a1 = *(const float4*)&As[kk][((ty + h) & 15) * 8 + 4];
        const float4 bv = *(const float4*)&Bs[kk][(((tx >> 1) + h) & 7) * 8 + (tx & 1) * 4];
        const float a[8] = {a0.x, a0.y, a0.z, a0.w, a1.x, a1.y, a1.z, a1.w};
        const float b[4] = {bv.x, bv.y, bv.z, bv.w};
#pragma unroll
        for (int i = 0; i < 8; ++i)
#pragma unroll
            for (int j = 0; j < 4; ++j)
                acc[i][j] = fmaf(a[i], b[j], acc[i][j]);
    }
}

// direct stage of one 32-wide K-chunk, A/B both row-major [rows][k] (A@B^T form)
__device__ __forceinline__ void stageT(const float* pA, const float* pB,
                                       float (*As)[PA], float (*Bs)[PB],
                                       int kq, int r0) {
    float4 va[4], vb[2];
#pragma unroll
    for (int i = 0; i < 4; ++i) va[i] = *(const float4*)(pA + (size_t)(32 * i) * DIM);
#pragma unroll
    for (int i = 0; i < 2; ++i) vb[i] = *(const float4*)(pB + (size_t)(32 * i) * DIM);
    const int c0 = kq * 4, hh = kq & 3;
#pragma unroll
    for (int i = 0; i < 4; ++i) {
        const int r = r0 + 32 * i;
        const int col = (((r >> 3) + hh) & 15) * 8 + (r & 7);   // octet-rotation swizzle
        As[c0 + 0][col] = va[i].x; As[c0 + 1][col] = va[i].y;
        As[c0 + 2][col] = va[i].z; As[c0 + 3][col] = va[i].w;
    }
#pragma unroll
    for (int i = 0; i < 2; ++i) {
        const int n = r0 + 32 * i;
        const int col = (((n >> 3) + hh) & 7) * 8 + (n & 7);
        Bs[c0 + 0][col] = vb[i].x; Bs[c0 + 1][col] = vb[i].y;
        Bs[c0 + 2][col] = vb[i].z; Bs[c0 + 3][col] = vb[i].w;
    }
}

// ---------------- K1: y = X @ Pi^T ; argmin -> idxf + idx8 ----------------
__global__ __launch_bounds__(256) void k1_rot_quant(
    const float* __restrict__ X, const float* __restrict__ Pi, const float* __restrict__ C,
    float* __restrict__ idxf, unsigned char* __restrict__ idx8)
{
    __shared__ float As[32][PA];
    __shared__ float Bs[32][PB];
    const int tid = threadIdx.x, tx = tid & 15, ty = tid >> 4;
    const int kq = tid & 7, r0 = tid >> 3;
    const int m0 = blockIdx.y * 128, n0 = blockIdx.x * 64;
    const float* pA = X  + (size_t)(m0 + r0) * DIM + kq * 4;
    const float* pB = Pi + (size_t)(n0 + r0) * DIM + kq * 4;
    float acc1[8][4] = {}, acc2[8][4] = {};
    for (int t = 0; t < 32; ++t) {
        stageT(pA + t * 32, pB + t * 32, As, Bs, kq, r0);
        __syncthreads();
        if (t < 16) computeT(As, Bs, tx, ty, acc1);
        else        computeT(As, Bs, tx, ty, acc2);
        __syncthreads();
    }
    float c8[8];
#pragma unroll
    for (int t = 0; t < 8; ++t) c8[t] = C[t];
#pragma unroll
    for (int i = 0; i < 8; ++i) {
        const size_t o = (size_t)(m0 + ty * 8 + i) * DIM + n0 + tx * 4;
        float fv[4]; unsigned char bv[4];
#pragma unroll
        for (int j = 0; j < 4; ++j) {
            const float y = acc1[i][j] + acc2[i][j];   // fl(p1+p2)
            float best = fabsf(y - c8[0]); int bi = 0;
#pragma unroll
            for (int t2 = 1; t2 < 8; ++t2) {
                const float d = fabsf(y - c8[t2]);
                if (d < best) { best = d; bi = t2; }   // strict <: np first-min tie rule
            }
            fv[j] = (float)bi; bv[j] = (unsigned char)bi;
        }
        *(float4*)&idxf[o] = make_float4(fv[0], fv[1], fv[2], fv[3]);
        *(uchar4*)&idx8[o] = make_uchar4(bv[0], bv[1], bv[2], bv[3]);
    }
}

// ---------------- K3: xhat = yhat @ Pi ; R = X - xhat ; fused row-norm partials ----------------
__global__ __launch_bounds__(256) void k3_unrot_residual(
    const float* __restrict__ X, const float* __restrict__ Pi, const float* __restrict__ C,
    const unsigned char* __restrict__ idx8, float* __restrict__ R, double* __restrict__ nrm2)
{
    __shared__ float As[32][PA];
    __shared__ float Bs[32][PB];
    __shared__ float clut[8];
    const int tid = threadIdx.x, tx = tid & 15, ty = tid >> 4;
    const int kq = tid & 7, r0 = tid >> 3;
    const int nq = tid & 15, kr0 = tid >> 4;
    const int m0 = blockIdx.y * 128, n0 = blockIdx.x * 64;
    if (tid < 8) clut[tid] = C[tid];
    __syncthreads();
    const unsigned char* pA = idx8 + (size_t)(m0 + r0) * DIM + kq * 4;
    const float*         pB = Pi + (size_t)kr0 * DIM + n0 + nq * 4;
    float acc1[8][4] = {}, acc2[8][4] = {};
    for (int t = 0; t < 32; ++t) {
        {   // direct stage: A = clut gather (swizzled), B = Pi rows (linear)
            uchar4 ka[4]; float4 kb[2];
#pragma unroll
            for (int i = 0; i < 4; ++i) ka[i] = *(const uchar4*)(pA + t * 32 + (size_t)(32 * i) * DIM);
#pragma unroll
            for (int i = 0; i < 2; ++i) kb[i] = *(const float4*)(pB + (size_t)(t * 32 + 16 * i) * DIM);
            const int c0 = kq * 4, hh = kq & 3;
#pragma unroll
            for (int i = 0; i < 4; ++i) {
                const int r = r0 + 32 * i;
                const int col = (((r >> 3) + hh) & 15) * 8 + (r & 7);
                As[c0 + 0][col] = clut[ka[i].x]; As[c0 + 1][col] = clut[ka[i].y];
                As[c0 + 2][col] = clut[ka[i].z]; As[c0 + 3][col] = clut[ka[i].w];
            }
            *(float4*)&Bs[kr0][nq * 4]      = kb[0];
            *(float4*)&Bs[kr0 + 16][nq * 4] = kb[1];
        }
        __syncthreads();
#pragma unroll
        for (int kk = 0; kk < 32; ++kk) {
            const int h = (kk >> 2) & 3;
            const float4 a0 = *(const float4*)&As[kk][((ty + h) & 15) * 8];
            const float4 a1 = *(const float4*)&As[kk][((ty + h) & 15) * 8 + 4];
            const float4 bv = *(const float4*)&Bs[kk][tx * 4];
            const float a[8] = {a0.x, a0.y, a0.z, a0.w, a1.x, a1.y, a1.z, a1.w};
            const float b[4] = {bv.x, bv.y, bv.z, bv.w};
            if (t < 16) {
#pragma unroll
                for (int i = 0; i < 8; ++i)
#pragma unroll
                    for (int j = 0; j < 4; ++j) acc1[i][j] = fmaf(a[i], b[j], acc1[i][j]);
            } else {
#pragma unroll
                for (int i = 0; i < 8; ++i)
#pragma unroll
                    for (int j = 0; j < 4; ++j) acc2[i][j] = fmaf(a[i], b[j], acc2[i][j]);
            }
        }
        __syncthreads();
    }
#pragma unroll
    for (int i = 0; i < 8; ++i) {
        const int row = m0 + ty * 8 + i;
        const size_t o = (size_t)row * DIM + n0 + tx * 4;
        const float4 xv = *(const float4*)&X[o];
        const float r0v = xv.x - (acc1[i][0] + acc2[i][0]);
        const float r1v = xv.y - (acc1[i][1] + acc2[i][1]);
        const float r2v = xv.z - (acc1[i][2] + acc2[i][2]);
        const float r3v = xv.w - (acc1[i][3] + acc2[i][3]);
        *(float4*)&R[o] = make_float4(r0v, r1v, r2v, r3v);
        double s = (double)r0v * r0v;
        s = fma((double)r1v, (double)r1v, s);
        s = fma((double)r2v, (double)r2v, s);
        s = fma((double)r3v, (double)r3v, s);
#pragma unroll
        for (int mask = 1; mask < 16; mask <<= 1) s += __shfl_xor(s, mask, 16);
        if (tx == 0) atomicAdd(&nrm2[row], s);
    }
}

// ---------------- K5: P = R @ S^T ; sign ----------------
__global__ __launch_bounds__(256) void k5_qjl(
    const float* __restrict__ R, const float* __restrict__ S, float* __restrict__ sgn)
{
    __shared__ float As[32][PA];
    __shared__ float Bs[32][PB];
    const int tid = threadIdx.x, tx = tid & 15, ty = tid >> 4;
    const int kq = tid & 7, r0 = tid >> 3;
    const int m0 = blockIdx.y * 128, n0 = blockIdx.x * 64;
    const float* pA = R + (size_t)(m0 + r0) * DIM + kq * 4;
    const float* pB = S + (size_t)(n0 + r0) * DIM + kq * 4;
    float acc1[8][4] = {}, acc2[8][4] = {};
    for (int t = 0; t < 32; ++t) {
        stageT(pA + t * 32, pB + t * 32, As, Bs, kq, r0);
        __syncthreads();
        if (t < 16) computeT(As, Bs, tx, ty, acc1);
        else        computeT(As, Bs, tx, ty, acc2);
        __syncthreads();
    }
#pragma unroll
    for (int i = 0; i < 8; ++i) {
        const size_t o = (size_t)(m0 + ty * 8 + i) * DIM + n0 + tx * 4;
        const float p0 = acc1[i][0] + acc2[i][0], p1 = acc1[i][1] + acc2[i][1];
        const float p2 = acc1[i][2] + acc2[i][2], p3 = acc1[i][3] + acc2[i][3];
        *(float4*)&sgn[o] = make_float4((p0 >= 0.f) ? 1.f : -1.f, (p1 >= 0.f) ? 1.f : -1.f,
                                        (p2 >= 0.f) ? 1.f : -1.f, (p3 >= 0.f) ? 1.f : -1.f);
    }
}

// ---------------- KN: norms = sqrt(nrm2) ----------------
__global__ __launch_bounds__(256) void kN_sqrt(const double* __restrict__ nrm2, float* __restrict__ nrm)
{
    const int i = blockIdx.x * 256 + threadIdx.x;
    if (i < B_ROWS) nrm[i] = (float)sqrt(nrm2[i]);
}

extern "C" void kernel_launch(void* const* d_in, const int* in_sizes, int n_in,
                              void* d_out, int out_size, void* d_ws, size_t ws_size,
                              hipStream_t stream) {
    const float* X  = (const float*)d_in[0];
    const float* Pi = (const float*)d_in[1];
    const float* C  = (const float*)d_in[2];
    const float* S  = (const float*)d_in[3];

    float* out  = (float*)d_out;
    float* idxf = out;                                   // B*D (index values)
    float* sgn  = out + (size_t)B_ROWS * DIM;            // B*D (+-1)
    float* nrm  = sgn + (size_t)B_ROWS * DIM;            // B

    char* ws = (char*)d_ws;
    float*         R    = (float*)ws;                                          // 128 MiB
    unsigned char* idx8 = (unsigned char*)(ws + (size_t)B_ROWS * DIM * 4);     //  32 MiB
    double*        nrm2 = (double*)(ws + (size_t)B_ROWS * DIM * 5);            // 256 KiB

    hipMemsetAsync(nrm2, 0, (size_t)B_ROWS * sizeof(double), stream);

    dim3 blk(256);
    dim3 gG(DIM / 64, B_ROWS / 128);                     // 16 x 256 = 4096 blocks

    k1_rot_quant     <<<gG, blk, 0, stream>>>(X, Pi, C, idxf, idx8);
    k3_unrot_residual<<<gG, blk, 0, stream>>>(X, Pi, C, idx8, R, nrm2);
    kN_sqrt          <<<dim3(B_ROWS / 256), blk, 0, stream>>>(nrm2, nrm);
    k5_qjl           <<<gG, blk, 0, stream>>>(R, S, sgn);
}

// Round 15
// 2911.927 us; speedup vs baseline: 1.3571x; 1.3571x over previous
//
#include <hip/hip_runtime.h>
#include <math.h>

#define B_ROWS 32768
#define DIM    1024
#define PA 132
#define PB 68
#define LDSF (2*32*PA + 2*32*PB)   // 12800 floats = 51.2 KB

// Numerics contract (verified r10-r14, absmax 0.0): BLIS sgemm, KC=512.
// Per C element: p1 = serial ascending FMA chain k=0..511, p2 = k=512..1023,
// C = fl(p1+p2).
//
// Structure (r12-r14 lessons): VGPR must stay <= 128 or waves/SIMD halve.
// Dual accumulators (64 regs) forbid prefetch ILP within that budget, so the
// two K-panels are split across the two 256-thread halves of a 512-thread
// block: each half owns ONE panel (acc = 32 regs) + a 24-reg prefetch
// fragment. Panels combine at the end via LDS ([elem][thread] layout,
// conflict-free). No swizzle (costs ~45 VGPR; conflicts measured ~0.003% of
// cycles - irrelevant).

struct FragT { float4 a0, a1, a2, a3, b0, b1; };

__device__ __forceinline__ void loadT(const float* pA, const float* pB, FragT& f) {
    f.a0 = *(const float4*)(pA);
    f.a1 = *(const float4*)(pA + (size_t)32 * DIM);
    f.a2 = *(const float4*)(pA + (size_t)64 * DIM);
    f.a3 = *(const float4*)(pA + (size_t)96 * DIM);
    f.b0 = *(const float4*)(pB);
    f.b1 = *(const float4*)(pB + (size_t)32 * DIM);
}

__device__ __forceinline__ void storeT(const FragT& f, float (*As)[PA], float (*Bs)[PB],
                                       int kq, int r0) {
    const int c0 = kq * 4;
#pragma unroll
    for (int i = 0; i < 4; ++i) {
        const float4 v = (i == 0) ? f.a0 : (i == 1) ? f.a1 : (i == 2) ? f.a2 : f.a3;
        const int r = r0 + 32 * i;
        As[c0 + 0][r] = v.x; As[c0 + 1][r] = v.y;
        As[c0 + 2][r] = v.z; As[c0 + 3][r] = v.w;
    }
#pragma unroll
    for (int i = 0; i < 2; ++i) {
        const float4 v = (i == 0) ? f.b0 : f.b1;
        const int n = r0 + 32 * i;
        Bs[c0 + 0][n] = v.x; Bs[c0 + 1][n] = v.y;
        Bs[c0 + 2][n] = v.z; Bs[c0 + 3][n] = v.w;
    }
}

__device__ __forceinline__ void computeT(const float (*As)[PA], const float (*Bs)[PB],
                                         int tx, int ty, float (&acc)[8][4]) {
#pragma unroll
    for (int kk = 0; kk < 32; ++kk) {
        const float4 a0 = *(const float4*)&As[kk][ty * 8];
        const float4 a1 = *(const float4*)&As[kk][ty * 8 + 4];
        const float4 bv = *(const float4*)&Bs[kk][tx * 4];
        const float a[8] = {a0.x, a0.y, a0.z, a0.w, a1.x, a1.y, a1.z, a1.w};
        const float b[4] = {bv.x, bv.y, bv.z, bv.w};
#pragma unroll
        for (int i = 0; i < 8; ++i)
#pragma unroll
            for (int j = 0; j < 4; ++j)
                acc[i][j] = fmaf(a[i], b[j], acc[i][j]);
    }
}

// ---------------- K1: y = X @ Pi^T ; argmin -> idxf + idx8 ----------------
__global__ __launch_bounds__(512) void k1_rot_quant(
    const float* __restrict__ X, const float* __restrict__ Pi, const float* __restrict__ C,
    float* __restrict__ idxf, unsigned char* __restrict__ idx8)
{
    __shared__ float lds[LDSF];
    const int tid = threadIdx.x, pan = tid >> 8, pt = tid & 255;
    float (*As)[PA] = (float(*)[PA])(lds + pan * 32 * PA);
    float (*Bs)[PB] = (float(*)[PB])(lds + 2 * 32 * PA + pan * 32 * PB);
    const int tx = pt & 15, ty = pt >> 4;
    const int kq = pt & 7, r0 = pt >> 3;
    const int m0 = blockIdx.y * 128, n0 = blockIdx.x * 64;
    const float* pA = X  + (size_t)(m0 + r0) * DIM + pan * 512 + kq * 4;
    const float* pB = Pi + (size_t)(n0 + r0) * DIM + pan * 512 + kq * 4;
    float acc[8][4] = {};
    FragT f;
    loadT(pA, pB, f);
    for (int t = 0; t < 16; ++t) {
        __syncthreads();
        storeT(f, As, Bs, kq, r0);
        __syncthreads();
        if (t < 15) loadT(pA + (t + 1) * 32, pB + (t + 1) * 32, f);   // hidden under compute
        computeT(As, Bs, tx, ty, acc);
    }
    __syncthreads();
    if (pan == 1) {
#pragma unroll
        for (int i = 0; i < 8; ++i)
#pragma unroll
            for (int j = 0; j < 4; ++j)
                lds[(i * 4 + j) * 256 + pt] = acc[i][j];     // [elem][thread]: bank = pt&31
    }
    __syncthreads();
    if (pan == 0) {
        float c8[8];
#pragma unroll
        for (int t = 0; t < 8; ++t) c8[t] = C[t];
#pragma unroll
        for (int i = 0; i < 8; ++i) {
            const size_t o = (size_t)(m0 + ty * 8 + i) * DIM + n0 + tx * 4;
            float fv[4]; unsigned char bv[4];
#pragma unroll
            for (int j = 0; j < 4; ++j) {
                const float y = acc[i][j] + lds[(i * 4 + j) * 256 + pt];   // fl(p1+p2)
                float best = fabsf(y - c8[0]); int bi = 0;
#pragma unroll
                for (int t2 = 1; t2 < 8; ++t2) {
                    const float d = fabsf(y - c8[t2]);
                    if (d < best) { best = d; bi = t2; }   // strict <: np first-min tie rule
                }
                fv[j] = (float)bi; bv[j] = (unsigned char)bi;
            }
            *(float4*)&idxf[o] = make_float4(fv[0], fv[1], fv[2], fv[3]);
            *(uchar4*)&idx8[o] = make_uchar4(bv[0], bv[1], bv[2], bv[3]);
        }
    }
}

// ---------------- K3: xhat = yhat @ Pi ; R = X - xhat ; fused row-norm partials ----------------
__global__ __launch_bounds__(512) void k3_unrot_residual(
    const float* __restrict__ X, const float* __restrict__ Pi, const float* __restrict__ C,
    const unsigned char* __restrict__ idx8, float* __restrict__ R, double* __restrict__ nrm2)
{
    __shared__ float lds[LDSF];
    __shared__ float clut[8];
    const int tid = threadIdx.x, pan = tid >> 8, pt = tid & 255;
    float (*As)[PA] = (float(*)[PA])(lds + pan * 32 * PA);
    float (*Bs)[PB] = (float(*)[PB])(lds + 2 * 32 * PA + pan * 32 * PB);
    const int tx = pt & 15, ty = pt >> 4;
    const int kq = pt & 7, r0 = pt >> 3;
    const int nq = pt & 15, kr0 = pt >> 4;
    const int m0 = blockIdx.y * 128, n0 = blockIdx.x * 64;
    if (tid < 8) clut[tid] = C[tid];
    const unsigned char* pA = idx8 + (size_t)(m0 + r0) * DIM + pan * 512 + kq * 4;
    const float*         pB = Pi + (size_t)(pan * 512 + kr0) * DIM + n0 + nq * 4;
    float acc[8][4] = {};
    uchar4 ka[4]; float4 kb[2];
#pragma unroll
    for (int i = 0; i < 4; ++i) ka[i] = *(const uchar4*)(pA + (size_t)(32 * i) * DIM);
    kb[0] = *(const float4*)(pB);
    kb[1] = *(const float4*)(pB + (size_t)16 * DIM);
    for (int t = 0; t < 16; ++t) {
        __syncthreads();
        {
            const int c0 = kq * 4;
#pragma unroll
            for (int i = 0; i < 4; ++i) {
                const int r = r0 + 32 * i;
                As[c0 + 0][r] = clut[ka[i].x]; As[c0 + 1][r] = clut[ka[i].y];
                As[c0 + 2][r] = clut[ka[i].z]; As[c0 + 3][r] = clut[ka[i].w];
            }
            *(float4*)&Bs[kr0][nq * 4]      = kb[0];
            *(float4*)&Bs[kr0 + 16][nq * 4] = kb[1];
        }
        __syncthreads();
        if (t < 15) {
#pragma unroll
            for (int i = 0; i < 4; ++i) ka[i] = *(const uchar4*)(pA + (t + 1) * 32 + (size_t)(32 * i) * DIM);
            kb[0] = *(const float4*)(pB + (size_t)((t + 1) * 32) * DIM);
            kb[1] = *(const float4*)(pB + (size_t)((t + 1) * 32 + 16) * DIM);
        }
        computeT(As, Bs, tx, ty, acc);
    }
    __syncthreads();
    if (pan == 1) {
#pragma unroll
        for (int i = 0; i < 8; ++i)
#pragma unroll
            for (int j = 0; j < 4; ++j)
                lds[(i * 4 + j) * 256 + pt] = acc[i][j];
    }
    __syncthreads();
    if (pan == 0) {
#pragma unroll
        for (int i = 0; i < 8; ++i) {
            const int row = m0 + ty * 8 + i;
            const size_t o = (size_t)row * DIM + n0 + tx * 4;
            const float4 xv = *(const float4*)&X[o];
            const float r0v = xv.x - (acc[i][0] + lds[(i * 4 + 0) * 256 + pt]);
            const float r1v = xv.y - (acc[i][1] + lds[(i * 4 + 1) * 256 + pt]);
            const float r2v = xv.z - (acc[i][2] + lds[(i * 4 + 2) * 256 + pt]);
            const float r3v = xv.w - (acc[i][3] + lds[(i * 4 + 3) * 256 + pt]);
            *(float4*)&R[o] = make_float4(r0v, r1v, r2v, r3v);
            double s = (double)r0v * r0v;
            s = fma((double)r1v, (double)r1v, s);
            s = fma((double)r2v, (double)r2v, s);
            s = fma((double)r3v, (double)r3v, s);
#pragma unroll
            for (int mask = 1; mask < 16; mask <<= 1) s += __shfl_xor(s, mask, 16);
            if (tx == 0) atomicAdd(&nrm2[row], s);
        }
    }
}

// ---------------- K5: P = R @ S^T ; sign ----------------
__global__ __launch_bounds__(512) void k5_qjl(
    const float* __restrict__ R, const float* __restrict__ S, float* __restrict__ sgn)
{
    __shared__ float lds[LDSF];
    const int tid = threadIdx.x, pan = tid >> 8, pt = tid & 255;
    float (*As)[PA] = (float(*)[PA])(lds + pan * 32 * PA);
    float (*Bs)[PB] = (float(*)[PB])(lds + 2 * 32 * PA + pan * 32 * PB);
    const int tx = pt & 15, ty = pt >> 4;
    const int kq = pt & 7, r0 = pt >> 3;
    const int m0 = blockIdx.y * 128, n0 = blockIdx.x * 64;
    const float* pA = R + (size_t)(m0 + r0) * DIM + pan * 512 + kq * 4;
    const float* pB = S + (size_t)(n0 + r0) * DIM + pan * 512 + kq * 4;
    float acc[8][4] = {};
    FragT f;
    loadT(pA, pB, f);
    for (int t = 0; t < 16; ++t) {
        __syncthreads();
        storeT(f, As, Bs, kq, r0);
        __syncthreads();
        if (t < 15) loadT(pA + (t + 1) * 32, pB + (t + 1) * 32, f);
        computeT(As, Bs, tx, ty, acc);
    }
    __syncthreads();
    if (pan == 1) {
#pragma unroll
        for (int i = 0; i < 8; ++i)
#pragma unroll
            for (int j = 0; j < 4; ++j)
                lds[(i * 4 + j) * 256 + pt] = acc[i][j];
    }
    __syncthreads();
    if (pan == 0) {
#pragma unroll
        for (int i = 0; i < 8; ++i) {
            const size_t o = (size_t)(m0 + ty * 8 + i) * DIM + n0 + tx * 4;
            const float p0 = acc[i][0] + lds[(i * 4 + 0) * 256 + pt];
            const float p1 = acc[i][1] + lds[(i * 4 + 1) * 256 + pt];
            const float p2 = acc[i][2] + lds[(i * 4 + 2) * 256 + pt];
            const float p3 = acc[i][3] + lds[(i * 4 + 3) * 256 + pt];
            *(float4*)&sgn[o] = make_float4((p0 >= 0.f) ? 1.f : -1.f, (p1 >= 0.f) ? 1.f : -1.f,
                                            (p2 >= 0.f) ? 1.f : -1.f, (p3 >= 0.f) ? 1.f : -1.f);
        }
    }
}

// ---------------- KN: norms = sqrt(nrm2) ----------------
__global__ __launch_bounds__(256) void kN_sqrt(const double* __restrict__ nrm2, float* __restrict__ nrm)
{
    const int i = blockIdx.x * 256 + threadIdx.x;
    if (i < B_ROWS) nrm[i] = (float)sqrt(nrm2[i]);
}

extern "C" void kernel_launch(void* const* d_in, const int* in_sizes, int n_in,
                              void* d_out, int out_size, void* d_ws, size_t ws_size,
                              hipStream_t stream) {
    const float* X  = (const float*)d_in[0];
    const float* Pi = (const float*)d_in[1];
    const float* C  = (const float*)d_in[2];
    const float* S  = (const float*)d_in[3];

    float* out  = (float*)d_out;
    float* idxf = out;                                   // B*D (index values)
    float* sgn  = out + (size_t)B_ROWS * DIM;            // B*D (+-1)
    float* nrm  = sgn + (size_t)B_ROWS * DIM;            // B

    char* ws = (char*)d_ws;
    float*         R    = (float*)ws;                                          // 128 MiB
    unsigned char* idx8 = (unsigned char*)(ws + (size_t)B_ROWS * DIM * 4);     //  32 MiB
    double*        nrm2 = (double*)(ws + (size_t)B_ROWS * DIM * 5);            // 256 KiB

    hipMemsetAsync(nrm2, 0, (size_t)B_ROWS * sizeof(double), stream);

    dim3 blk(512);
    dim3 gG(DIM / 64, B_ROWS / 128);                     // 16 x 256 = 4096 blocks

    k1_rot_quant     <<<gG, blk, 0, stream>>>(X, Pi, C, idxf, idx8);
    k3_unrot_residual<<<gG, blk, 0, stream>>>(X, Pi, C, idx8, R, nrm2);
    kN_sqrt          <<<dim3(B_ROWS / 256), dim3(256), 0, stream>>>(nrm2, nrm);
    k5_qjl           <<<gG, blk, 0, stream>>>(R, S, sgn);
}

// Round 16
// 2813.123 us; speedup vs baseline: 1.4048x; 1.0351x over previous
//
#include <hip/hip_runtime.h>
#include <math.h>

#define B_ROWS 32768
#define DIM    1024
#define PAD    132
#define LDSF   (2*2*32*PAD)   // 2 panels * (A+B) * 32*132 floats = 67.6 KB

// Numerics contract (verified r10-r15, absmax 0.0): BLIS sgemm, KC=512.
// Per C element: p1 = serial ascending FMA chain k=0..511, p2 = k=512..1023,
// C = fl(p1+p2). Panel p held by block-half `pan`; combined via LDS at end.
//
// r15 analysis: 8x4 tile is LDS-read-pipe-bound (3 b128/kk for 32 FMA ->
// 576 LDS cyc vs 256 SIMD cyc per kk per CU). This round: 8x8 tile
// (4 b128/kk for 64 FMA) halves LDS+barrier+staging cost per FLOP.
// VGPR budget: acc 64 + prefetch 32 + addr ~16 ~= 115 < 128 bucket.

struct FragT { float4 a0, a1, a2, a3, b0, b1, b2, b3; };

__device__ __forceinline__ void loadT(const float* pA, const float* pB, FragT& f) {
    f.a0 = *(const float4*)(pA);
    f.a1 = *(const float4*)(pA + (size_t)32 * DIM);
    f.a2 = *(const float4*)(pA + (size_t)64 * DIM);
    f.a3 = *(const float4*)(pA + (size_t)96 * DIM);
    f.b0 = *(const float4*)(pB);
    f.b1 = *(const float4*)(pB + (size_t)32 * DIM);
    f.b2 = *(const float4*)(pB + (size_t)64 * DIM);
    f.b3 = *(const float4*)(pB + (size_t)96 * DIM);
}

__device__ __forceinline__ void storeT(const FragT& f, float (*As)[PAD], float (*Bs)[PAD],
                                       int kq, int r0) {
    const int c0 = kq * 4;
#pragma unroll
    for (int i = 0; i < 4; ++i) {
        const float4 v = (i == 0) ? f.a0 : (i == 1) ? f.a1 : (i == 2) ? f.a2 : f.a3;
        const int r = r0 + 32 * i;
        As[c0 + 0][r] = v.x; As[c0 + 1][r] = v.y;
        As[c0 + 2][r] = v.z; As[c0 + 3][r] = v.w;
    }
#pragma unroll
    for (int i = 0; i < 4; ++i) {
        const float4 v = (i == 0) ? f.b0 : (i == 1) ? f.b1 : (i == 2) ? f.b2 : f.b3;
        const int r = r0 + 32 * i;
        Bs[c0 + 0][r] = v.x; Bs[c0 + 1][r] = v.y;
        Bs[c0 + 2][r] = v.z; Bs[c0 + 3][r] = v.w;
    }
}

__device__ __forceinline__ void computeT(const float (*As)[PAD], const float (*Bs)[PAD],
                                         int tx, int ty, float (&acc)[8][8]) {
#pragma unroll
    for (int kk = 0; kk < 32; ++kk) {
        const float4 a0 = *(const float4*)&As[kk][ty * 8];
        const float4 a1 = *(const float4*)&As[kk][ty * 8 + 4];
        const float4 b0 = *(const float4*)&Bs[kk][tx * 8];
        const float4 b1 = *(const float4*)&Bs[kk][tx * 8 + 4];
        const float a[8] = {a0.x, a0.y, a0.z, a0.w, a1.x, a1.y, a1.z, a1.w};
        const float b[8] = {b0.x, b0.y, b0.z, b0.w, b1.x, b1.y, b1.z, b1.w};
#pragma unroll
        for (int i = 0; i < 8; ++i)
#pragma unroll
            for (int j = 0; j < 8; ++j)
                acc[i][j] = fmaf(a[i], b[j], acc[i][j]);
    }
}

// ---------------- K1: y = X @ Pi^T ; argmin -> idxf + idx8 ----------------
__global__ __launch_bounds__(512) void k1_rot_quant(
    const float* __restrict__ X, const float* __restrict__ Pi, const float* __restrict__ C,
    float* __restrict__ idxf, unsigned char* __restrict__ idx8)
{
    __shared__ float lds[LDSF];
    const int tid = threadIdx.x, pan = tid >> 8, pt = tid & 255;
    float (*As)[PAD] = (float(*)[PAD])(lds + pan * 32 * PAD);
    float (*Bs)[PAD] = (float(*)[PAD])(lds + 2 * 32 * PAD + pan * 32 * PAD);
    const int tx = pt & 15, ty = pt >> 4;
    const int kq = pt & 7, r0 = pt >> 3;
    const int m0 = blockIdx.y * 128, n0 = blockIdx.x * 128;
    const float* pA = X  + (size_t)(m0 + r0) * DIM + pan * 512 + kq * 4;
    const float* pB = Pi + (size_t)(n0 + r0) * DIM + pan * 512 + kq * 4;
    float acc[8][8] = {};
    FragT f;
    loadT(pA, pB, f);
    for (int t = 0; t < 16; ++t) {
        __syncthreads();
        storeT(f, As, Bs, kq, r0);
        __syncthreads();
        if (t < 15) loadT(pA + (t + 1) * 32, pB + (t + 1) * 32, f);
        computeT(As, Bs, tx, ty, acc);
    }
    __syncthreads();
    if (pan == 1) {
#pragma unroll
        for (int i = 0; i < 8; ++i)
#pragma unroll
            for (int j = 0; j < 8; ++j)
                lds[(i * 8 + j) * 256 + pt] = acc[i][j];
    }
    __syncthreads();
    if (pan == 0) {
        float c8[8];
#pragma unroll
        for (int t = 0; t < 8; ++t) c8[t] = C[t];
#pragma unroll
        for (int i = 0; i < 8; ++i) {
            const size_t o = (size_t)(m0 + ty * 8 + i) * DIM + n0 + tx * 8;
            float fv[8]; unsigned char bv[8];
#pragma unroll
            for (int j = 0; j < 8; ++j) {
                const float y = acc[i][j] + lds[(i * 8 + j) * 256 + pt];   // fl(p1+p2)
                float best = fabsf(y - c8[0]); int bi = 0;
#pragma unroll
                for (int t2 = 1; t2 < 8; ++t2) {
                    const float d = fabsf(y - c8[t2]);
                    if (d < best) { best = d; bi = t2; }   // strict <: np first-min tie
                }
                fv[j] = (float)bi; bv[j] = (unsigned char)bi;
            }
            *(float4*)&idxf[o]     = make_float4(fv[0], fv[1], fv[2], fv[3]);
            *(float4*)&idxf[o + 4] = make_float4(fv[4], fv[5], fv[6], fv[7]);
            *(uchar4*)&idx8[o]     = make_uchar4(bv[0], bv[1], bv[2], bv[3]);
            *(uchar4*)&idx8[o + 4] = make_uchar4(bv[4], bv[5], bv[6], bv[7]);
        }
    }
}

// ---------------- K3: xhat = yhat @ Pi ; R = X - xhat ; fused norm partials ----------------
__global__ __launch_bounds__(512) void k3_unrot_residual(
    const float* __restrict__ X, const float* __restrict__ Pi, const float* __restrict__ C,
    const unsigned char* __restrict__ idx8, float* __restrict__ R, double* __restrict__ nrm2)
{
    __shared__ float lds[LDSF];
    __shared__ float clut[8];
    const int tid = threadIdx.x, pan = tid >> 8, pt = tid & 255;
    float (*As)[PAD] = (float(*)[PAD])(lds + pan * 32 * PAD);
    float (*Bs)[PAD] = (float(*)[PAD])(lds + 2 * 32 * PAD + pan * 32 * PAD);
    const int tx = pt & 15, ty = pt >> 4;
    const int kq = pt & 7, r0 = pt >> 3;
    const int nq = pt & 31, kr0 = pt >> 5;                 // B-staging map (32 k x 128 n)
    const int m0 = blockIdx.y * 128, n0 = blockIdx.x * 128;
    if (tid < 8) clut[tid] = C[tid];
    const unsigned char* pA = idx8 + (size_t)(m0 + r0) * DIM + pan * 512 + kq * 4;
    const float*         pB = Pi + (size_t)(pan * 512 + kr0) * DIM + n0 + nq * 4;
    float acc[8][8] = {};
    uchar4 ka[4]; float4 kb[4];
#pragma unroll
    for (int i = 0; i < 4; ++i) ka[i] = *(const uchar4*)(pA + (size_t)(32 * i) * DIM);
#pragma unroll
    for (int i = 0; i < 4; ++i) kb[i] = *(const float4*)(pB + (size_t)(8 * i) * DIM);
    for (int t = 0; t < 16; ++t) {
        __syncthreads();
        {
            const int c0 = kq * 4;
#pragma unroll
            for (int i = 0; i < 4; ++i) {
                const int r = r0 + 32 * i;
                As[c0 + 0][r] = clut[ka[i].x]; As[c0 + 1][r] = clut[ka[i].y];
                As[c0 + 2][r] = clut[ka[i].z]; As[c0 + 3][r] = clut[ka[i].w];
            }
#pragma unroll
            for (int i = 0; i < 4; ++i)
                *(float4*)&Bs[kr0 + 8 * i][nq * 4] = kb[i];
        }
        __syncthreads();
        if (t < 15) {
#pragma unroll
            for (int i = 0; i < 4; ++i)
                ka[i] = *(const uchar4*)(pA + (t + 1) * 32 + (size_t)(32 * i) * DIM);
#pragma unroll
            for (int i = 0; i < 4; ++i)
                kb[i] = *(const float4*)(pB + (size_t)((t + 1) * 32 + 8 * i) * DIM);
        }
        computeT(As, Bs, tx, ty, acc);
    }
    __syncthreads();
    if (pan == 1) {
#pragma unroll
        for (int i = 0; i < 8; ++i)
#pragma unroll
            for (int j = 0; j < 8; ++j)
                lds[(i * 8 + j) * 256 + pt] = acc[i][j];
    }
    __syncthreads();
    if (pan == 0) {
#pragma unroll
        for (int i = 0; i < 8; ++i) {
            const int row = m0 + ty * 8 + i;
            const size_t o = (size_t)row * DIM + n0 + tx * 8;
            const float4 x0 = *(const float4*)&X[o];
            const float4 x1 = *(const float4*)&X[o + 4];
            float rv[8];
            rv[0] = x0.x - (acc[i][0] + lds[(i * 8 + 0) * 256 + pt]);
            rv[1] = x0.y - (acc[i][1] + lds[(i * 8 + 1) * 256 + pt]);
            rv[2] = x0.z - (acc[i][2] + lds[(i * 8 + 2) * 256 + pt]);
            rv[3] = x0.w - (acc[i][3] + lds[(i * 8 + 3) * 256 + pt]);
            rv[4] = x1.x - (acc[i][4] + lds[(i * 8 + 4) * 256 + pt]);
            rv[5] = x1.y - (acc[i][5] + lds[(i * 8 + 5) * 256 + pt]);
            rv[6] = x1.z - (acc[i][6] + lds[(i * 8 + 6) * 256 + pt]);
            rv[7] = x1.w - (acc[i][7] + lds[(i * 8 + 7) * 256 + pt]);
            *(float4*)&R[o]     = make_float4(rv[0], rv[1], rv[2], rv[3]);
            *(float4*)&R[o + 4] = make_float4(rv[4], rv[5], rv[6], rv[7]);
            double s = 0.0;
#pragma unroll
            for (int j = 0; j < 8; ++j) s = fma((double)rv[j], (double)rv[j], s);
#pragma unroll
            for (int mask = 1; mask < 16; mask <<= 1) s += __shfl_xor(s, mask, 16);
            if (tx == 0) atomicAdd(&nrm2[row], s);
        }
    }
}

// ---------------- K5: P = R @ S^T ; sign ----------------
__global__ __launch_bounds__(512) void k5_qjl(
    const float* __restrict__ R, const float* __restrict__ S, float* __restrict__ sgn)
{
    __shared__ float lds[LDSF];
    const int tid = threadIdx.x, pan = tid >> 8, pt = tid & 255;
    float (*As)[PAD] = (float(*)[PAD])(lds + pan * 32 * PAD);
    float (*Bs)[PAD] = (float(*)[PAD])(lds + 2 * 32 * PAD + pan * 32 * PAD);
    const int tx = pt & 15, ty = pt >> 4;
    const int kq = pt & 7, r0 = pt >> 3;
    const int m0 = blockIdx.y * 128, n0 = blockIdx.x * 128;
    const float* pA = R + (size_t)(m0 + r0) * DIM + pan * 512 + kq * 4;
    const float* pB = S + (size_t)(n0 + r0) * DIM + pan * 512 + kq * 4;
    float acc[8][8] = {};
    FragT f;
    loadT(pA, pB, f);
    for (int t = 0; t < 16; ++t) {
        __syncthreads();
        storeT(f, As, Bs, kq, r0);
        __syncthreads();
        if (t < 15) loadT(pA + (t + 1) * 32, pB + (t + 1) * 32, f);
        computeT(As, Bs, tx, ty, acc);
    }
    __syncthreads();
    if (pan == 1) {
#pragma unroll
        for (int i = 0; i < 8; ++i)
#pragma unroll
            for (int j = 0; j < 8; ++j)
                lds[(i * 8 + j) * 256 + pt] = acc[i][j];
    }
    __syncthreads();
    if (pan == 0) {
#pragma unroll
        for (int i = 0; i < 8; ++i) {
            const size_t o = (size_t)(m0 + ty * 8 + i) * DIM + n0 + tx * 8;
            float pv[8];
#pragma unroll
            for (int j = 0; j < 8; ++j) pv[j] = acc[i][j] + lds[(i * 8 + j) * 256 + pt];
            *(float4*)&sgn[o]     = make_float4((pv[0] >= 0.f) ? 1.f : -1.f, (pv[1] >= 0.f) ? 1.f : -1.f,
                                                (pv[2] >= 0.f) ? 1.f : -1.f, (pv[3] >= 0.f) ? 1.f : -1.f);
            *(float4*)&sgn[o + 4] = make_float4((pv[4] >= 0.f) ? 1.f : -1.f, (pv[5] >= 0.f) ? 1.f : -1.f,
                                                (pv[6] >= 0.f) ? 1.f : -1.f, (pv[7] >= 0.f) ? 1.f : -1.f);
        }
    }
}

// ---------------- KN: norms = sqrt(nrm2) ----------------
__global__ __launch_bounds__(256) void kN_sqrt(const double* __restrict__ nrm2, float* __restrict__ nrm)
{
    const int i = blockIdx.x * 256 + threadIdx.x;
    if (i < B_ROWS) nrm[i] = (float)sqrt(nrm2[i]);
}

extern "C" void kernel_launch(void* const* d_in, const int* in_sizes, int n_in,
                              void* d_out, int out_size, void* d_ws, size_t ws_size,
                              hipStream_t stream) {
    const float* X  = (const float*)d_in[0];
    const float* Pi = (const float*)d_in[1];
    const float* C  = (const float*)d_in[2];
    const float* S  = (const float*)d_in[3];

    float* out  = (float*)d_out;
    float* idxf = out;                                   // B*D (index values)
    float* sgn  = out + (size_t)B_ROWS * DIM;            // B*D (+-1)
    float* nrm  = sgn + (size_t)B_ROWS * DIM;            // B

    char* ws = (char*)d_ws;
    float*         R    = (float*)ws;                                          // 128 MiB
    unsigned char* idx8 = (unsigned char*)(ws + (size_t)B_ROWS * DIM * 4);     //  32 MiB
    double*        nrm2 = (double*)(ws + (size_t)B_ROWS * DIM * 5);            // 256 KiB

    hipMemsetAsync(nrm2, 0, (size_t)B_ROWS * sizeof(double), stream);

    dim3 blk(512);
    dim3 gG(DIM / 128, B_ROWS / 128);                    // 8 x 256 = 2048 blocks

    k1_rot_quant     <<<gG, blk, 0, stream>>>(X, Pi, C, idxf, idx8);
    k3_unrot_residual<<<gG, blk, 0, stream>>>(X, Pi, C, idx8, R, nrm2);
    kN_sqrt          <<<dim3(B_ROWS / 256), dim3(256), 0, stream>>>(nrm2, nrm);
    k5_qjl           <<<gG, blk, 0, stream>>>(R, S, sgn);
}